// Round 7
// baseline (334.080 us; speedup 1.0000x reference)
//
#include <hip/hip_runtime.h>
#include <hip/hip_cooperative_groups.h>
#include <math.h>

namespace cg = cooperative_groups;

// Problem dims (fixed by the reference)
#define B_ 8
#define L_ 8192
#define H_ 128
#define N_ 32
#define C_ 128   // chunks along L
#define T_ 64    // chunk length

// ws layout:
//   Wh   ushort[256*128]     @ 0        (64 KB)  fp16 out_w [g][h]
//   gy   ushort[B_*H_*L_]    @ 3211264  (16 MB)  fp16 gy [b][h][l'], l'=t*128+c
//   part float[1024]         @ 19988480 (4 KB)
// R7: single cooperative dispatch (phaseA=s4d, grid.sync, phaseB=mix,
//     grid.sync, phaseC=final). Launch overhead ~10us/dispatch dominated the
//     controllable budget (R1/R6 evidence); grid.sync is the harness-blessed
//     fusion mechanism (unlike the R2/R5 ad-hoc atomic tails that serialized
//     on one TCC cacheline). Non-cooperative 3-kernel fallback kept.

typedef _Float16 half8 __attribute__((ext_vector_type(8)));
typedef __attribute__((ext_vector_type(4))) float f32x4;

__device__ __forceinline__ float gelu_tanh(float y) {
    float t = 0.7978845608028654f * fmaf(0.044715f, y * y * y, y);
    float e = __expf(2.f * t);
    float th = 1.f - __fdividef(2.f, e + 1.f);
    return 0.5f * y * (1.f + th);
}
__device__ __forceinline__ unsigned short f2h(float f) {
    _Float16 h = (_Float16)f;
    return *(unsigned short*)&h;
}
__device__ __forceinline__ float h2f(unsigned short u) {
    return (float)(*(const _Float16*)&u);
}
__device__ __forceinline__ unsigned int pk2(float a, float b) {
    return (unsigned)f2h(a) | ((unsigned)f2h(b) << 16);
}

// ---------------------------------------------------------------------------
// phaseA: MFMA-Toeplitz S4D for one (b,h) block (body = R6 k_s4d).
// ---------------------------------------------------------------------------
__device__ __forceinline__ void phaseA(
    unsigned short (*Ut)[72], char* scratch, float2 (*wTpow)[N_],
    float2* coefs, float2* ArAi, float* Kd,
    const float* __restrict__ x, const float* __restrict__ enc_w,
    const float* __restrict__ enc_b, const float* __restrict__ log_dt,
    const float* __restrict__ log_A_real, const float* __restrict__ A_imag,
    const float* __restrict__ C_re, const float* __restrict__ C_im,
    const float* __restrict__ Dp, const float* __restrict__ out_w,
    unsigned short* __restrict__ Wh, unsigned short* __restrict__ gy,
    int bh, int tid)
{
    const int b = bh >> 7, h = bh & (H_ - 1);
    const int lane = tid & 63, wq = tid >> 6;
    const int mrow = lane & 15, quad = lane >> 4;

    unsigned short* E16 = (unsigned short*)scratch;   // [c(128)][m(64)] stride 72
    float2*         Sx  = (float2*)scratch;           // [n(32)][c(64)]
    unsigned short* St  = (unsigned short*)scratch;   // [c(128)][m'] stride 72

    const float dt = expf(log_dt[h]);
    const float Dh = Dp[h];

    if (tid < N_) {
        int n = tid;
        float Ar = -expf(log_A_real[h * N_ + n]);
        float Ai = A_imag[h * N_ + n];
        ArAi[n] = make_float2(Ar, Ai);
        // coefs = C * (w - 1) / A
        float ar = dt * Ar, ai = dt * Ai;
        float er = expf(ar);
        float wr = er * cosf(ai), wi = er * sinf(ai);
        float inv = 1.f / (Ar * Ar + Ai * Ai);
        float numr = wr - 1.f, numi = wi;
        float qr = (numr * Ar + numi * Ai) * inv;
        float qi = (numi * Ar - numr * Ai) * inv;
        coefs[n] = make_float2(C_re[h * N_ + n] * qr - C_im[h * N_ + n] * qi,
                               C_re[h * N_ + n] * qi + C_im[h * N_ + n] * qr);
        // wTpow: w^(T*2^k) for the chunk scan
        float arT = dt * Ar * (float)T_, aiT = dt * Ai * (float)T_;
        float erT = expf(arT);
        float pr = erT * cosf(aiT), pi = erT * sinf(aiT);
#pragma unroll
        for (int k = 0; k < 7; ++k) {
            wTpow[k][n] = make_float2(pr, pi);
            float nr = pr * pr - pi * pi;
            pi = 2.f * pr * pi; pr = nr;
        }
    }

    if (b == 0) {   // out_w rows g = 2h, 2h+1 -> fp16 (for phaseB)
        int g = 2 * h + (tid >> 7), j = tid & 127;
        Wh[g * 128 + j] = f2h(out_w[g * 128 + j]);
    }

    // ---- stage: u = enc(x) -> Ut[c][j] fp16 ----
    const float ew0 = enc_w[h], ew1 = enc_w[H_ + h], eb = enc_b[h];
    {
        int c = tid >> 1, j0 = (tid & 1) * 32;
        const float4* xp = (const float4*)((const float2*)x + (size_t)b * L_
                                           + c * 64 + j0);
#pragma unroll
        for (int i = 0; i < 16; ++i) {
            float4 xv = xp[i];
            float u0 = fmaf(xv.x, ew0, fmaf(xv.y, ew1, eb));
            float u1 = fmaf(xv.z, ew0, fmaf(xv.w, ew1, eb));
            *(unsigned int*)&Ut[c][j0 + 2 * i] = pk2(u0, u1);
        }
    }
    __syncthreads();

    // ---- Kd partials: Kd[t] = 2*sum_n Re(coef_n * w_n^t); 4 partials/t ----
    {
        int t = tid >> 2, q = tid & 3;
        float s = 0.f;
        float ft = (float)t;
#pragma unroll
        for (int k = 0; k < 8; ++k) {
            int n = q * 8 + k;
            float2 cf = coefs[n]; float2 aa = ArAi[n];
            float er = __expf(dt * aa.x * ft);
            float sn, cs; __sincosf(dt * aa.y * ft, &sn, &cs);
            s = fmaf(cf.x, er * cs, s);
            s = fmaf(-cf.y, er * sn, s);
        }
        ((float*)&Ut[t][64])[q] = s;   // row padding, bank-clean
    }

    // ---- GEMM E[m 64][c 128] = V[m][j] @ U[j][c]; V per-element trig ----
    {
        f32x4 acc[8];
#pragma unroll
        for (int nt = 0; nt < 8; ++nt) acc[nt] = (f32x4){0.f, 0.f, 0.f, 0.f};
        const int m = wq * 16 + mrow;        // V row: thread-private
        const float2 aa = ArAi[m & 31];
        const float dAr = dt * aa.x, dAi = dt * aa.y;
        const bool isIm = (m >= 32);         // uniform per wave
#pragma unroll
        for (int ks = 0; ks < 2; ++ks) {
            int k0 = ks * 32 + quad * 8;
            half8 af;
#pragma unroll
            for (int i = 0; i < 8; ++i) {
                float d = (float)(63 - (k0 + i));   // V[m][j] = w_n^(63-j)
                float er = __expf(dAr * d);
                float sn, cs; __sincosf(dAi * d, &sn, &cs);
                af[i] = (_Float16)(isIm ? er * sn : er * cs);
            }
#pragma unroll
            for (int nt = 0; nt < 8; ++nt) {
                half8 bf = *(const half8*)&Ut[nt * 16 + mrow][k0];
                acc[nt] = __builtin_amdgcn_mfma_f32_16x16x32_f16(
                    af, bf, acc[nt], 0, 0, 0);
            }
        }
        // packed store: E16[cc][m0..m0+3] as one b64
        const int m0 = wq * 16 + quad * 4;
#pragma unroll
        for (int nt = 0; nt < 8; ++nt) {
            int cc = nt * 16 + mrow;
            unsigned long long w =
                (unsigned long long)pk2(acc[nt][0], acc[nt][1]) |
                ((unsigned long long)pk2(acc[nt][2], acc[nt][3]) << 32);
            *(unsigned long long*)&E16[cc * 72 + m0] = w;
        }
    }
    __syncthreads();

    if (tid < 64) {   // reduce Kd partials; fold D into the Toeplitz diagonal
        const float* kp = (const float*)&Ut[tid][64];
        Kd[tid] = 2.f * (kp[0] + kp[1] + kp[2] + kp[3])
                  + ((tid == 0) ? Dh : 0.f);
    }

    // ---- scan: 4 waves, wave = (cHalf, nHalf), 16 n per thread ----
    float zr[16], zi[16];
    const int cHalf = wq & 1, nHalf = wq >> 1;
    const int n0 = nHalf * 16;
    const int c = cHalf * 64 + lane;
    {   // vector loads: E16[c][n0..n0+15] (re), [c][32+n0..] (im)
        half8 ha = *(const half8*)(E16 + c * 72 + n0);
        half8 hb = *(const half8*)(E16 + c * 72 + n0 + 8);
        half8 hc = *(const half8*)(E16 + c * 72 + 32 + n0);
        half8 hd = *(const half8*)(E16 + c * 72 + 32 + n0 + 8);
#pragma unroll
        for (int j = 0; j < 8; ++j) {
            zr[j] = (float)ha[j];  zr[8 + j] = (float)hb[j];
            zi[j] = (float)hc[j];  zi[8 + j] = (float)hd[j];
        }
    }
    __syncthreads();            // all E16 reads done before Sx overwrites
#pragma unroll
    for (int k = 0; k < 6; ++k) {
        int s = 1 << k;
        float mask = (lane >= s) ? 1.f : 0.f;
#pragma unroll
        for (int j = 0; j < 16; ++j) {
            float2 q = wTpow[k][n0 + j];
            float vr = __shfl_up(zr[j], s, 64);
            float vi = __shfl_up(zi[j], s, 64);
            float adr = fmaf(q.x, vr, -(q.y * vi));
            float adi = fmaf(q.x, vi, q.y * vr);
            zr[j] = fmaf(mask, adr, zr[j]);
            zi[j] = fmaf(mask, adi, zi[j]);
        }
    }
    if (cHalf == 0) {           // publish inclusive scans of low c-half
#pragma unroll
        for (int j = 0; j < 16; ++j)
            Sx[(n0 + j) * 64 + lane] = make_float2(zr[j], zi[j]);
    }
    __syncthreads();
    if (cHalf == 1) {           // s=64 combine with uniform weight wT^64
#pragma unroll
        for (int j = 0; j < 16; ++j) {
            float2 q = wTpow[6][n0 + j];
            float2 v = Sx[(n0 + j) * 64 + lane];
            zr[j] = fmaf(q.x, v.x, fmaf(-q.y, v.y, zr[j]));
            zi[j] = fmaf(q.x, v.y, fmaf(q.y, v.x, zi[j]));
        }
    }
    {                           // shift by one chunk: S_in[c] = I[c-1]
        bool l0 = (lane == 0);
#pragma unroll
        for (int j = 0; j < 16; ++j) {
            float2 bv = Sx[(n0 + j) * 64 + 63];
            float br = (cHalf == 1) ? bv.x : 0.f;
            float bi = (cHalf == 1) ? bv.y : 0.f;
            float tr = __shfl_up(zr[j], 1, 64);
            float ti = __shfl_up(zi[j], 1, 64);
            zr[j] = l0 ? br : tr;
            zi[j] = l0 ? bi : ti;
        }
    }
    __syncthreads();            // all Sx reads done before St overwrites
    {   // packed publish: 4 x b128
        uint4 w0, w1;
        w0.x = pk2(zr[0], zr[1]);   w0.y = pk2(zr[2], zr[3]);
        w0.z = pk2(zr[4], zr[5]);   w0.w = pk2(zr[6], zr[7]);
        w1.x = pk2(zr[8], zr[9]);   w1.y = pk2(zr[10], zr[11]);
        w1.z = pk2(zr[12], zr[13]); w1.w = pk2(zr[14], zr[15]);
        *(uint4*)&St[c * 72 + n0] = w0;
        *(uint4*)&St[c * 72 + n0 + 8] = w1;
        w0.x = pk2(zi[0], zi[1]);   w0.y = pk2(zi[2], zi[3]);
        w0.z = pk2(zi[4], zi[5]);   w0.w = pk2(zi[6], zi[7]);
        w1.x = pk2(zi[8], zi[9]);   w1.y = pk2(zi[10], zi[11]);
        w1.z = pk2(zi[12], zi[13]); w1.w = pk2(zi[14], zi[15]);
        *(uint4*)&St[c * 72 + 32 + n0] = w0;
        *(uint4*)&St[c * 72 + 32 + n0 + 8] = w1;
    }
    __syncthreads();

    // ---- GEMM Y^T[c][t] = U^T@Klo^T + S^T@P^T (operand-swapped MFMA) ----
    {
        f32x4 acc[8];
#pragma unroll
        for (int nt = 0; nt < 8; ++nt) acc[nt] = (f32x4){0.f, 0.f, 0.f, 0.f};
        const int t = wq * 16 + mrow;        // B-side col: thread-private
#pragma unroll
        for (int ks = 0; ks < 2; ++ks) {
            int k0 = ks * 32 + quad * 8;
            half8 af;
#pragma unroll
            for (int i = 0; i < 8; ++i) {
                int j = k0 + i;
                af[i] = (_Float16)((t >= j) ? Kd[t - j] : 0.f);
            }
#pragma unroll
            for (int nt = 0; nt < 8; ++nt) {
                half8 bf = *(const half8*)&Ut[nt * 16 + mrow][k0];
                acc[nt] = __builtin_amdgcn_mfma_f32_16x16x32_f16(
                    bf, af, acc[nt], 0, 0, 0);       // swapped
            }
        }
        // P synth after Kd GEMM (short live range)
        half8 afP0, afP1;
        {
            float tp1 = (float)(t + 1);
#pragma unroll
            for (int i = 0; i < 8; ++i) {
                int n = quad * 8 + i;
                float2 cf = coefs[n]; float2 aa = ArAi[n];
                float er = __expf(dt * aa.x * tp1);
                float sn, cs; __sincosf(dt * aa.y * tp1, &sn, &cs);
                float wr = er * cs, wi = er * sn;
                afP0[i] = (_Float16)( 2.f * (cf.x * wr - cf.y * wi));
                afP1[i] = (_Float16)(-2.f * (cf.x * wi + cf.y * wr));
            }
        }
#pragma unroll
        for (int ks = 0; ks < 2; ++ks) {
            int k0 = ks * 32 + quad * 8;
            half8 af = ks ? afP1 : afP0;
#pragma unroll
            for (int nt = 0; nt < 8; ++nt) {
                half8 bf = *(const half8*)&St[(nt * 16 + mrow) * 72 + k0];
                acc[nt] = __builtin_amdgcn_mfma_f32_16x16x32_f16(
                    bf, af, acc[nt], 0, 0, 0);       // swapped
            }
        }
        // epilogue: t fixed; cc = nt*16 + quad*4 + r -> packed b64
        unsigned short* gyr = gy + (size_t)bh * L_ + (size_t)t * 128;
#pragma unroll
        for (int nt = 0; nt < 8; ++nt) {
            float g0 = gelu_tanh(acc[nt][0]);
            float g1 = gelu_tanh(acc[nt][1]);
            float g2 = gelu_tanh(acc[nt][2]);
            float g3 = gelu_tanh(acc[nt][3]);
            unsigned long long w =
                (unsigned long long)pk2(g0, g1) |
                ((unsigned long long)pk2(g2, g3) << 32);
            *(unsigned long long*)&gyr[nt * 16 + quad * 4] = w;
        }
    }
}

// ---------------------------------------------------------------------------
// phaseB: fp16 MFMA GLU mix + pooled decode for one (b,t,ch) tile (= R6 k_mix).
// ---------------------------------------------------------------------------
__device__ __forceinline__ void phaseB(
    unsigned short* Bt, float* red,
    const unsigned short* __restrict__ Wh, const unsigned short* __restrict__ gy,
    const float* __restrict__ out_b, const float* __restrict__ dec_w,
    float* __restrict__ part, int blk, int tid)
{
    const int b = blk >> 7;
    const int t = (blk >> 1) & 63, ch = blk & 1;
    const int wq = tid >> 6, lane = tid & 63;

    // ---- stage: 128h x 64v fp16 transpose, 16B-unit index ^= (v>>3) ----
    const unsigned short* gsrc = gy + (size_t)(b * H_) * L_ + t * 128 + ch * 64;
#pragma unroll
    for (int it = 0; it < 4; ++it) {
        int idx = it * 256 + tid;
        int h = idx >> 3, v0 = (idx & 7) * 8;
        uint4 q = *(const uint4*)(gsrc + (size_t)h * L_ + v0);
        const int sw = (((h >> 3) ^ (idx & 7)) << 3) | (h & 7);
        Bt[(v0 + 0) * 128 + sw] = (unsigned short)(q.x & 0xFFFF);
        Bt[(v0 + 1) * 128 + sw] = (unsigned short)(q.x >> 16);
        Bt[(v0 + 2) * 128 + sw] = (unsigned short)(q.y & 0xFFFF);
        Bt[(v0 + 3) * 128 + sw] = (unsigned short)(q.y >> 16);
        Bt[(v0 + 4) * 128 + sw] = (unsigned short)(q.z & 0xFFFF);
        Bt[(v0 + 5) * 128 + sw] = (unsigned short)(q.z >> 16);
        Bt[(v0 + 6) * 128 + sw] = (unsigned short)(q.w & 0xFFFF);
        Bt[(v0 + 7) * 128 + sw] = (unsigned short)(q.w >> 16);
    }
    __syncthreads();

    const int ga = wq * 32;
    const int gg = 128 + wq * 32;
    const int mrow = lane & 15;
    const int quad = lane >> 4;
    f32x4 accA[2][4], accG[2][4];
#pragma unroll
    for (int mt = 0; mt < 2; ++mt)
#pragma unroll
        for (int nt = 0; nt < 4; ++nt) {
            accA[mt][nt] = (f32x4){0.f, 0.f, 0.f, 0.f};
            accG[mt][nt] = (f32x4){0.f, 0.f, 0.f, 0.f};
        }

#pragma unroll
    for (int k = 0; k < 4; ++k) {
        const int h0 = k * 32 + quad * 8;
        half8 bfr[4];
#pragma unroll
        for (int nt = 0; nt < 4; ++nt) {
            int v = nt * 16 + mrow;
            bfr[nt] = *(const half8*)&Bt[v * 128 +
                                         (((4 * k + quad) ^ (v >> 3)) << 3)];
        }
#pragma unroll
        for (int mt = 0; mt < 2; ++mt) {
            half8 ah = *(const half8*)(Wh + (ga + mt * 16 + mrow) * 128 + h0);
            half8 ag = *(const half8*)(Wh + (gg + mt * 16 + mrow) * 128 + h0);
#pragma unroll
            for (int nt = 0; nt < 4; ++nt) {
                accA[mt][nt] = __builtin_amdgcn_mfma_f32_16x16x32_f16(
                    ah, bfr[nt], accA[mt][nt], 0, 0, 0);
                accG[mt][nt] = __builtin_amdgcn_mfma_f32_16x16x32_f16(
                    ag, bfr[nt], accG[mt][nt], 0, 0, 0);
            }
        }
    }

    float s = 0.f;
#pragma unroll
    for (int mt = 0; mt < 2; ++mt) {
        float4 obA = *(const float4*)(out_b + ga + mt * 16 + quad * 4);
        float4 obG = *(const float4*)(out_b + gg + mt * 16 + quad * 4);
        float4 dv  = *(const float4*)(dec_w + ga + mt * 16 + quad * 4);
#pragma unroll
        for (int nt = 0; nt < 4; ++nt) {
#pragma unroll
            for (int r = 0; r < 4; ++r) {
                float a  = accA[mt][nt][r] + ((const float*)&obA)[r];
                float zg = accG[mt][nt][r] + ((const float*)&obG)[r];
                float sig = __fdividef(1.f, 1.f + __expf(-zg));
                s = fmaf(((const float*)&dv)[r], a * sig, s);
            }
        }
    }
#pragma unroll
    for (int off = 32; off; off >>= 1) s += __shfl_down(s, off, 64);
    if (lane == 0) red[wq] = s;
    __syncthreads();
    if (tid == 0) part[blk] = red[0] + red[1] + red[2] + red[3];
}

// ---------------------------------------------------------------------------
__device__ __forceinline__ void phaseC(
    const float* __restrict__ part, const float* __restrict__ dec_b,
    float* __restrict__ out, int tid)
{
    int b2 = tid >> 5, i = tid & 31;
    float sum = 0.f;
#pragma unroll
    for (int k = 0; k < 4; ++k)
        sum += part[b2 * 128 + i + 32 * k];
#pragma unroll
    for (int off = 16; off; off >>= 1) sum += __shfl_down(sum, off, 32);
    if (i == 0) out[b2] = fmaf(sum, 1.0f / (float)L_, dec_b[0]);
}

// ---------------------------------------------------------------------------
// k_all: single cooperative dispatch. grid = 1024 = B_*H_ = B_*128.
// LDS 39.4 KB -> 4 blocks/CU; launch_bounds(256,4) caps VGPR<=128 so all
// 1024 blocks are co-resident (required for grid.sync).
// ---------------------------------------------------------------------------
__global__ __launch_bounds__(256, 4) void k_all(
    const float* __restrict__ x, const float* __restrict__ enc_w,
    const float* __restrict__ enc_b, const float* __restrict__ log_dt,
    const float* __restrict__ log_A_real, const float* __restrict__ A_imag,
    const float* __restrict__ C_re, const float* __restrict__ C_im,
    const float* __restrict__ Dp, const float* __restrict__ out_w,
    const float* __restrict__ out_b, const float* __restrict__ dec_w,
    const float* __restrict__ dec_b,
    unsigned short* __restrict__ Wh, unsigned short* __restrict__ gy,
    float* __restrict__ part, float* __restrict__ out)
{
    __shared__ unsigned short Ut[C_][72];
    __shared__ __align__(16) char scratch[18432];
    __shared__ float2 wTpow[7][N_];
    __shared__ float2 coefs[N_];
    __shared__ float2 ArAi[N_];
    __shared__ float  Kd[64];
    __shared__ float  red[4];

    const int tid = threadIdx.x;
    phaseA(Ut, scratch, wTpow, coefs, ArAi, Kd,
           x, enc_w, enc_b, log_dt, log_A_real, A_imag, C_re, C_im, Dp,
           out_w, Wh, gy, blockIdx.x, tid);
    cg::this_grid().sync();
    phaseB((unsigned short*)scratch, red, Wh, gy, out_b, dec_w, part,
           blockIdx.x, tid);
    cg::this_grid().sync();
    if (blockIdx.x == 0) phaseC(part, dec_b, out, tid);
}

// ---------------------------------------------------------------------------
// Fallback (non-cooperative) kernels — same device code, 3 dispatches.
// ---------------------------------------------------------------------------
__global__ __launch_bounds__(256, 4) void k_s4d(
    const float* __restrict__ x, const float* __restrict__ enc_w,
    const float* __restrict__ enc_b, const float* __restrict__ log_dt,
    const float* __restrict__ log_A_real, const float* __restrict__ A_imag,
    const float* __restrict__ C_re, const float* __restrict__ C_im,
    const float* __restrict__ Dp, const float* __restrict__ out_w,
    unsigned short* __restrict__ Wh, unsigned short* __restrict__ gy)
{
    __shared__ unsigned short Ut[C_][72];
    __shared__ __align__(16) char scratch[18432];
    __shared__ float2 wTpow[7][N_];
    __shared__ float2 coefs[N_];
    __shared__ float2 ArAi[N_];
    __shared__ float  Kd[64];
    phaseA(Ut, scratch, wTpow, coefs, ArAi, Kd,
           x, enc_w, enc_b, log_dt, log_A_real, A_imag, C_re, C_im, Dp,
           out_w, Wh, gy, blockIdx.x, threadIdx.x);
}

__global__ __launch_bounds__(256, 4) void k_mix(
    const unsigned short* __restrict__ Wh, const unsigned short* __restrict__ gy,
    const float* __restrict__ out_b, const float* __restrict__ dec_w,
    float* __restrict__ part)
{
    __shared__ unsigned short Bt[64 * 128];
    __shared__ float red[4];
    phaseB(Bt, red, Wh, gy, out_b, dec_w, part, blockIdx.x, threadIdx.x);
}

__global__ __launch_bounds__(256) void k_final(
    const float* __restrict__ part, const float* __restrict__ dec_b,
    float* __restrict__ out)
{
    phaseC(part, dec_b, out, threadIdx.x);
}

// ---------------------------------------------------------------------------
extern "C" void kernel_launch(void* const* d_in, const int* in_sizes, int n_in,
                              void* d_out, int out_size, void* d_ws, size_t ws_size,
                              hipStream_t stream)
{
    const float* x         = (const float*)d_in[0];
    const float* enc_w     = (const float*)d_in[1];
    const float* enc_b     = (const float*)d_in[2];
    const float* log_dt    = (const float*)d_in[3];
    const float* log_A_real= (const float*)d_in[4];
    const float* A_imag    = (const float*)d_in[5];
    const float* C_re      = (const float*)d_in[6];
    const float* C_im      = (const float*)d_in[7];
    const float* Dp        = (const float*)d_in[8];
    const float* out_w     = (const float*)d_in[9];
    const float* out_b     = (const float*)d_in[10];
    const float* dec_w     = (const float*)d_in[11];
    const float* dec_b     = (const float*)d_in[12];
    float* out = (float*)d_out;

    char* ws = (char*)d_ws;
    unsigned short* Wh = (unsigned short*)(ws);
    unsigned short* gy = (unsigned short*)(ws + 3211264);
    float* part        = (float*)(ws + 19988480);

    void* args[] = {
        (void*)&x, (void*)&enc_w, (void*)&enc_b, (void*)&log_dt,
        (void*)&log_A_real, (void*)&A_imag, (void*)&C_re, (void*)&C_im,
        (void*)&Dp, (void*)&out_w, (void*)&out_b, (void*)&dec_w,
        (void*)&dec_b, (void*)&Wh, (void*)&gy, (void*)&part, (void*)&out };

    hipError_t err = hipLaunchCooperativeKernel(
        (const void*)k_all, dim3(B_ * H_), dim3(256), args, 0, stream);
    if (err != hipSuccess) {
        // fallback: 3-dispatch path (R6 structure)
        k_s4d<<<B_ * H_, 256, 0, stream>>>(x, enc_w, enc_b, log_dt,
                                           log_A_real, A_imag, C_re, C_im,
                                           Dp, out_w, Wh, gy);
        k_mix<<<B_ * 128, 256, 0, stream>>>(Wh, gy, out_b, dec_w, part);
        k_final<<<1, 256, 0, stream>>>(part, dec_b, out);
    }
}

// Round 8
// 126.414 us; speedup vs baseline: 2.6427x; 2.6427x over previous
//
#include <hip/hip_runtime.h>
#include <math.h>

// Problem dims (fixed by the reference)
#define B_ 8
#define L_ 8192
#define H_ 128
#define N_ 32
#define C_ 128   // chunks along L
#define T_ 64    // chunk length

// ws layout:
//   Wh   ushort[256*128]     @ 0        (64 KB)  fp16 out_w [g][h]
//   gy   ushort[B_*H_*L_]    @ 3211264  (16 MB)  fp16 gy [b][h][l'], l'=t*128+c
//   part float[1024]         @ 19988480 (4 KB)
// R8: 3-dispatch structure is final (R2/R5/R7 fold attempts all regressed;
//     R7's grid.sync cost 100+us). R7's counters showed 2.75M LDS bank-
//     conflict cycles -> this round cuts k_s4d LDS-pipe work:
//     (1) enc staging 16 conflicted b32 -> 4 balanced ds_write_b128;
//     (2) scan restructured to c-pairs/thread, whole-128c per wave:
//         ds_bpermute count 208->112, Sx roundtrip + 1 barrier deleted;
//     (3) St publish b128 per (c, re/im).

typedef _Float16 half8 __attribute__((ext_vector_type(8)));
typedef __attribute__((ext_vector_type(4))) float f32x4;

__device__ __forceinline__ float gelu_tanh(float y) {
    float t = 0.7978845608028654f * fmaf(0.044715f, y * y * y, y);
    float e = __expf(2.f * t);
    float th = 1.f - __fdividef(2.f, e + 1.f);
    return 0.5f * y * (1.f + th);
}
__device__ __forceinline__ unsigned short f2h(float f) {
    _Float16 h = (_Float16)f;
    return *(unsigned short*)&h;
}
__device__ __forceinline__ float h2f(unsigned short u) {
    return (float)(*(const _Float16*)&u);
}
__device__ __forceinline__ unsigned int pk2(float a, float b) {
    return (unsigned)f2h(a) | ((unsigned)f2h(b) << 16);
}

// ---------------------------------------------------------------------------
// k_s4d: MFMA-Toeplitz S4D, in-register K/P/V synthesis.
// ---------------------------------------------------------------------------
__global__ __launch_bounds__(256, 4) void k_s4d(
    const float* __restrict__ x, const float* __restrict__ enc_w,
    const float* __restrict__ enc_b, const float* __restrict__ log_dt,
    const float* __restrict__ log_A_real, const float* __restrict__ A_imag,
    const float* __restrict__ C_re, const float* __restrict__ C_im,
    const float* __restrict__ Dp, const float* __restrict__ out_w,
    unsigned short* __restrict__ Wh, unsigned short* __restrict__ gy)
{
    const int bh = blockIdx.x;
    const int b = bh >> 7, h = bh & (H_ - 1);
    const int tid = threadIdx.x;
    const int lane = tid & 63, wq = tid >> 6;
    const int mrow = lane & 15, quad = lane >> 4;

    __shared__ unsigned short Ut[C_][72];          // [c][j] fp16 u; cols 64..71 = Kd partials
    __shared__ __align__(16) char scratch[18432];  // E16 / St (18.4 KB)
    __shared__ float2 wTpow[7][N_];                // 1.8 KB
    __shared__ float2 coefs[N_];                   // 256 B
    __shared__ float2 ArAi[N_];                    // 256 B
    __shared__ float  Kd[64];                      // 256 B
    unsigned short* E16 = (unsigned short*)scratch;   // [c(128)][m(64)] stride 72
    unsigned short* St  = (unsigned short*)scratch;   // [c(128)][m'] stride 72

    const float dt = expf(log_dt[h]);
    const float Dh = Dp[h];

    if (tid < N_) {
        int n = tid;
        float Ar = -expf(log_A_real[h * N_ + n]);
        float Ai = A_imag[h * N_ + n];
        ArAi[n] = make_float2(Ar, Ai);
        // coefs = C * (w - 1) / A
        float ar = dt * Ar, ai = dt * Ai;
        float er = expf(ar);
        float wr = er * cosf(ai), wi = er * sinf(ai);
        float inv = 1.f / (Ar * Ar + Ai * Ai);
        float numr = wr - 1.f, numi = wi;
        float qr = (numr * Ar + numi * Ai) * inv;
        float qi = (numi * Ar - numr * Ai) * inv;
        coefs[n] = make_float2(C_re[h * N_ + n] * qr - C_im[h * N_ + n] * qi,
                               C_re[h * N_ + n] * qi + C_im[h * N_ + n] * qr);
        // wTpow[k] = wT^(2^k), wT = exp(dt*A*T)
        float arT = dt * Ar * (float)T_, aiT = dt * Ai * (float)T_;
        float erT = expf(arT);
        float pr = erT * cosf(aiT), pi = erT * sinf(aiT);
#pragma unroll
        for (int k = 0; k < 7; ++k) {
            wTpow[k][n] = make_float2(pr, pi);
            float nr = pr * pr - pi * pi;
            pi = 2.f * pr * pi; pr = nr;
        }
    }

    if (b == 0) {   // out_w rows g = 2h, 2h+1 -> fp16 (for k_mix)
        int g = 2 * h + (tid >> 7), j = tid & 127;
        Wh[g * 128 + j] = f2h(out_w[g * 128 + j]);
    }

    // ---- stage: u = enc(x) -> Ut[c][j] fp16 (4 x b128, bank-balanced) ----
    const float ew0 = enc_w[h], ew1 = enc_w[H_ + h], eb = enc_b[h];
    {
        int c = tid >> 1, j0 = (tid & 1) * 32;
        const float4* xp = (const float4*)((const float2*)x + (size_t)b * L_
                                           + c * 64 + j0);
#pragma unroll
        for (int ii = 0; ii < 4; ++ii) {
            uint4 w;
            unsigned int* pw = (unsigned int*)&w;
#pragma unroll
            for (int q2 = 0; q2 < 4; ++q2) {
                float4 xv = xp[ii * 4 + q2];
                float u0 = fmaf(xv.x, ew0, fmaf(xv.y, ew1, eb));
                float u1 = fmaf(xv.z, ew0, fmaf(xv.w, ew1, eb));
                pw[q2] = pk2(u0, u1);
            }
            *(uint4*)&Ut[c][j0 + ii * 8] = w;
        }
    }
    __syncthreads();

    // ---- Kd partials: Kd[t] = 2*sum_n Re(coef_n * w_n^t); 4 partials/t ----
    {
        int t = tid >> 2, q = tid & 3;
        float s = 0.f;
        float ft = (float)t;
#pragma unroll
        for (int k = 0; k < 8; ++k) {
            int n = q * 8 + k;
            float2 cf = coefs[n]; float2 aa = ArAi[n];
            float er = __expf(dt * aa.x * ft);
            float sn, cs; __sincosf(dt * aa.y * ft, &sn, &cs);
            s = fmaf(cf.x, er * cs, s);
            s = fmaf(-cf.y, er * sn, s);
        }
        ((float*)&Ut[t][64])[q] = s;   // row padding, bank-clean
    }

    // ---- GEMM E[m 64][c 128] = V[m][j] @ U[j][c]; V per-element trig ----
    {
        f32x4 acc[8];
#pragma unroll
        for (int nt = 0; nt < 8; ++nt) acc[nt] = (f32x4){0.f, 0.f, 0.f, 0.f};
        const int m = wq * 16 + mrow;        // V row: thread-private
        const float2 aa = ArAi[m & 31];
        const float dAr = dt * aa.x, dAi = dt * aa.y;
        const bool isIm = (m >= 32);         // uniform per wave
#pragma unroll
        for (int ks = 0; ks < 2; ++ks) {
            int k0 = ks * 32 + quad * 8;
            half8 af;
#pragma unroll
            for (int i = 0; i < 8; ++i) {
                float d = (float)(63 - (k0 + i));   // V[m][j] = w_n^(63-j)
                float er = __expf(dAr * d);
                float sn, cs; __sincosf(dAi * d, &sn, &cs);
                af[i] = (_Float16)(isIm ? er * sn : er * cs);
            }
#pragma unroll
            for (int nt = 0; nt < 8; ++nt) {
                half8 bf = *(const half8*)&Ut[nt * 16 + mrow][k0];
                acc[nt] = __builtin_amdgcn_mfma_f32_16x16x32_f16(
                    af, bf, acc[nt], 0, 0, 0);
            }
        }
        // packed store: E16[cc][m0..m0+3] as one b64 (16-row: bank-free)
        const int m0 = wq * 16 + quad * 4;
#pragma unroll
        for (int nt = 0; nt < 8; ++nt) {
            int cc = nt * 16 + mrow;
            unsigned long long w =
                (unsigned long long)pk2(acc[nt][0], acc[nt][1]) |
                ((unsigned long long)pk2(acc[nt][2], acc[nt][3]) << 32);
            *(unsigned long long*)&E16[cc * 72 + m0] = w;
        }
    }
    __syncthreads();

    if (tid < 64) {   // reduce Kd partials; fold D into the Toeplitz diagonal
        const float* kp = (const float*)&Ut[tid][64];
        Kd[tid] = 2.f * (kp[0] + kp[1] + kp[2] + kp[3])
                  + ((tid == 0) ? Dh : 0.f);
    }

    // ---- scan: wave wq owns n-octet n0 = wq*8 for ALL 128 c; thread owns
    //      the c-pair (2*lane, 2*lane+1). I[c] = E[c] + wT*I[c-1]. ----
    float z0r[8], z0i[8], z1r[8], z1i[8], hpr[8], hpi[8];
    const int n0 = wq * 8;
    const int c0 = 2 * lane;
    {
        half8 ar_ = *(const half8*)(E16 + c0 * 72 + n0);
        half8 ai_ = *(const half8*)(E16 + c0 * 72 + 32 + n0);
        half8 br_ = *(const half8*)(E16 + (c0 + 1) * 72 + n0);
        half8 bi_ = *(const half8*)(E16 + (c0 + 1) * 72 + 32 + n0);
#pragma unroll
        for (int j = 0; j < 8; ++j) {
            z0r[j] = (float)ar_[j];  z0i[j] = (float)ai_[j];
            z1r[j] = (float)br_[j];  z1i[j] = (float)bi_[j];
        }
    }
    __syncthreads();            // all E16 reads done before St overwrites
    // pair combine: head z1 = E[c1] + wT*E[c0]
#pragma unroll
    for (int j = 0; j < 8; ++j) {
        float2 q = wTpow[0][n0 + j];
        z1r[j] = fmaf(q.x, z0r[j], fmaf(-q.y, z0i[j], z1r[j]));
        z1i[j] = fmaf(q.x, z0i[j], fmaf(q.y, z0r[j], z1i[j]));
    }
    // 64-block lane scan of heads, block ratio wT^2: weight wTpow[k], s=2^(k-1)
#pragma unroll
    for (int k = 1; k <= 6; ++k) {
        int s = 1 << (k - 1);
        float mask = (lane >= s) ? 1.f : 0.f;
#pragma unroll
        for (int j = 0; j < 8; ++j) {
            float2 q = wTpow[k][n0 + j];
            float vr = __shfl_up(z1r[j], s, 64);
            float vi = __shfl_up(z1i[j], s, 64);
            float adr = fmaf(q.x, vr, -(q.y * vi));
            float adi = fmaf(q.x, vi, q.y * vr);
            z1r[j] = fmaf(mask, adr, z1r[j]);
            z1i[j] = fmaf(mask, adi, z1i[j]);
        }
    }
    // Hprev = I[c0-1] (0 for lane 0); doubles as S_in[c0]
    {
        bool l0 = (lane == 0);
#pragma unroll
        for (int j = 0; j < 8; ++j) {
            float tr = __shfl_up(z1r[j], 1, 64);
            float ti = __shfl_up(z1i[j], 1, 64);
            hpr[j] = l0 ? 0.f : tr;
            hpi[j] = l0 ? 0.f : ti;
        }
    }
    // S_in[c0+1] = I[c0] = E[c0] + wT*Hprev  (into z0)
#pragma unroll
    for (int j = 0; j < 8; ++j) {
        float2 q = wTpow[0][n0 + j];
        z0r[j] = fmaf(q.x, hpr[j], fmaf(-q.y, hpi[j], z0r[j]));
        z0i[j] = fmaf(q.x, hpi[j], fmaf(q.y, hpr[j], z0i[j]));
    }
    {   // publish St[c][m']: one b128 per (c, re/im)
        uint4 w;
        w.x = pk2(hpr[0], hpr[1]); w.y = pk2(hpr[2], hpr[3]);
        w.z = pk2(hpr[4], hpr[5]); w.w = pk2(hpr[6], hpr[7]);
        *(uint4*)&St[c0 * 72 + n0] = w;
        w.x = pk2(hpi[0], hpi[1]); w.y = pk2(hpi[2], hpi[3]);
        w.z = pk2(hpi[4], hpi[5]); w.w = pk2(hpi[6], hpi[7]);
        *(uint4*)&St[c0 * 72 + 32 + n0] = w;
        w.x = pk2(z0r[0], z0r[1]); w.y = pk2(z0r[2], z0r[3]);
        w.z = pk2(z0r[4], z0r[5]); w.w = pk2(z0r[6], z0r[7]);
        *(uint4*)&St[(c0 + 1) * 72 + n0] = w;
        w.x = pk2(z0i[0], z0i[1]); w.y = pk2(z0i[2], z0i[3]);
        w.z = pk2(z0i[4], z0i[5]); w.w = pk2(z0i[6], z0i[7]);
        *(uint4*)&St[(c0 + 1) * 72 + 32 + n0] = w;
    }
    __syncthreads();

    // ---- GEMM Y^T[c][t] = U^T@Klo^T + S^T@P^T (operand-swapped MFMA) ----
    {
        f32x4 acc[8];
#pragma unroll
        for (int nt = 0; nt < 8; ++nt) acc[nt] = (f32x4){0.f, 0.f, 0.f, 0.f};
        const int t = wq * 16 + mrow;        // B-side col: thread-private
#pragma unroll
        for (int ks = 0; ks < 2; ++ks) {
            int k0 = ks * 32 + quad * 8;
            half8 af;
#pragma unroll
            for (int i = 0; i < 8; ++i) {
                int j = k0 + i;
                af[i] = (_Float16)((t >= j) ? Kd[t - j] : 0.f);
            }
#pragma unroll
            for (int nt = 0; nt < 8; ++nt) {
                half8 bf = *(const half8*)&Ut[nt * 16 + mrow][k0];
                acc[nt] = __builtin_amdgcn_mfma_f32_16x16x32_f16(
                    bf, af, acc[nt], 0, 0, 0);       // swapped
            }
        }
        // P synth after Kd GEMM (short live range)
        half8 afP0, afP1;
        {
            float tp1 = (float)(t + 1);
#pragma unroll
            for (int i = 0; i < 8; ++i) {
                int n = quad * 8 + i;
                float2 cf = coefs[n]; float2 aa = ArAi[n];
                float er = __expf(dt * aa.x * tp1);
                float sn, cs; __sincosf(dt * aa.y * tp1, &sn, &cs);
                float wr = er * cs, wi = er * sn;
                afP0[i] = (_Float16)( 2.f * (cf.x * wr - cf.y * wi));
                afP1[i] = (_Float16)(-2.f * (cf.x * wi + cf.y * wr));
            }
        }
#pragma unroll
        for (int ks = 0; ks < 2; ++ks) {
            int k0 = ks * 32 + quad * 8;
            half8 af = ks ? afP1 : afP0;
#pragma unroll
            for (int nt = 0; nt < 8; ++nt) {
                half8 bf = *(const half8*)&St[(nt * 16 + mrow) * 72 + k0];
                acc[nt] = __builtin_amdgcn_mfma_f32_16x16x32_f16(
                    bf, af, acc[nt], 0, 0, 0);       // swapped
            }
        }
        // epilogue: t fixed; cc = nt*16 + quad*4 + r -> packed b64
        unsigned short* gyr = gy + (size_t)bh * L_ + (size_t)t * 128;
#pragma unroll
        for (int nt = 0; nt < 8; ++nt) {
            float g0 = gelu_tanh(acc[nt][0]);
            float g1 = gelu_tanh(acc[nt][1]);
            float g2 = gelu_tanh(acc[nt][2]);
            float g3 = gelu_tanh(acc[nt][3]);
            unsigned long long w =
                (unsigned long long)pk2(g0, g1) |
                ((unsigned long long)pk2(g2, g3) << 32);
            *(unsigned long long*)&gyr[nt * 16 + quad * 4] = w;
        }
    }
}

// ---------------------------------------------------------------------------
// k_mix: fp16 MFMA GLU mix + pooled decode (unchanged from R6).
// ---------------------------------------------------------------------------
__global__ __launch_bounds__(256, 4) void k_mix(
    const unsigned short* __restrict__ Wh, const unsigned short* __restrict__ gy,
    const float* __restrict__ out_b, const float* __restrict__ dec_w,
    float* __restrict__ part)
{
    __shared__ unsigned short Bt[64 * 128];    // [v][h] swizzled (16 KB)
    __shared__ float red[4];

    const int blk = blockIdx.x;                // = b*128 + t*2 + ch
    const int b = blk >> 7;
    const int t = (blk >> 1) & 63, ch = blk & 1;
    const int tid = threadIdx.x;
    const int wq = tid >> 6, lane = tid & 63;

    // ---- stage: 128h x 64v fp16 transpose, 16B-unit index ^= (v>>3) ----
    const unsigned short* gsrc = gy + (size_t)(b * H_) * L_ + t * 128 + ch * 64;
#pragma unroll
    for (int it = 0; it < 4; ++it) {
        int idx = it * 256 + tid;
        int h = idx >> 3, v0 = (idx & 7) * 8;
        uint4 q = *(const uint4*)(gsrc + (size_t)h * L_ + v0);
        const int sw = (((h >> 3) ^ (idx & 7)) << 3) | (h & 7);
        Bt[(v0 + 0) * 128 + sw] = (unsigned short)(q.x & 0xFFFF);
        Bt[(v0 + 1) * 128 + sw] = (unsigned short)(q.x >> 16);
        Bt[(v0 + 2) * 128 + sw] = (unsigned short)(q.y & 0xFFFF);
        Bt[(v0 + 3) * 128 + sw] = (unsigned short)(q.y >> 16);
        Bt[(v0 + 4) * 128 + sw] = (unsigned short)(q.z & 0xFFFF);
        Bt[(v0 + 5) * 128 + sw] = (unsigned short)(q.z >> 16);
        Bt[(v0 + 6) * 128 + sw] = (unsigned short)(q.w & 0xFFFF);
        Bt[(v0 + 7) * 128 + sw] = (unsigned short)(q.w >> 16);
    }
    __syncthreads();

    const int ga = wq * 32;
    const int gg = 128 + wq * 32;
    const int mrow = lane & 15;
    const int quad = lane >> 4;
    f32x4 accA[2][4], accG[2][4];
#pragma unroll
    for (int mt = 0; mt < 2; ++mt)
#pragma unroll
        for (int nt = 0; nt < 4; ++nt) {
            accA[mt][nt] = (f32x4){0.f, 0.f, 0.f, 0.f};
            accG[mt][nt] = (f32x4){0.f, 0.f, 0.f, 0.f};
        }

#pragma unroll
    for (int k = 0; k < 4; ++k) {
        const int h0 = k * 32 + quad * 8;
        half8 bfr[4];
#pragma unroll
        for (int nt = 0; nt < 4; ++nt) {
            int v = nt * 16 + mrow;
            bfr[nt] = *(const half8*)&Bt[v * 128 +
                                         (((4 * k + quad) ^ (v >> 3)) << 3)];
        }
#pragma unroll
        for (int mt = 0; mt < 2; ++mt) {
            half8 ah = *(const half8*)(Wh + (ga + mt * 16 + mrow) * 128 + h0);
            half8 ag = *(const half8*)(Wh + (gg + mt * 16 + mrow) * 128 + h0);
#pragma unroll
            for (int nt = 0; nt < 4; ++nt) {
                accA[mt][nt] = __builtin_amdgcn_mfma_f32_16x16x32_f16(
                    ah, bfr[nt], accA[mt][nt], 0, 0, 0);
                accG[mt][nt] = __builtin_amdgcn_mfma_f32_16x16x32_f16(
                    ag, bfr[nt], accG[mt][nt], 0, 0, 0);
            }
        }
    }

    float s = 0.f;
#pragma unroll
    for (int mt = 0; mt < 2; ++mt) {
        float4 obA = *(const float4*)(out_b + ga + mt * 16 + quad * 4);
        float4 obG = *(const float4*)(out_b + gg + mt * 16 + quad * 4);
        float4 dv  = *(const float4*)(dec_w + ga + mt * 16 + quad * 4);
#pragma unroll
        for (int nt = 0; nt < 4; ++nt) {
#pragma unroll
            for (int r = 0; r < 4; ++r) {
                float a  = accA[mt][nt][r] + ((const float*)&obA)[r];
                float zg = accG[mt][nt][r] + ((const float*)&obG)[r];
                float sig = __fdividef(1.f, 1.f + __expf(-zg));
                s = fmaf(((const float*)&dv)[r], a * sig, s);
            }
        }
    }
#pragma unroll
    for (int off = 32; off; off >>= 1) s += __shfl_down(s, off, 64);
    if (lane == 0) red[wq] = s;
    __syncthreads();
    if (tid == 0) part[blk] = red[0] + red[1] + red[2] + red[3];
}

// ---------------------------------------------------------------------------
__global__ __launch_bounds__(512) void k_final(
    const float* __restrict__ part, const float* __restrict__ dec_b,
    float* __restrict__ out)
{
    int tid = threadIdx.x;
    int b = tid >> 6, lane = tid & 63;
    float s = part[b * 128 + lane] + part[b * 128 + 64 + lane];
#pragma unroll
    for (int off = 32; off; off >>= 1) s += __shfl_down(s, off, 64);
    if (lane == 0) out[b] = fmaf(s, 1.0f / (float)L_, dec_b[0]);
}

// ---------------------------------------------------------------------------
extern "C" void kernel_launch(void* const* d_in, const int* in_sizes, int n_in,
                              void* d_out, int out_size, void* d_ws, size_t ws_size,
                              hipStream_t stream)
{
    const float* x         = (const float*)d_in[0];
    const float* enc_w     = (const float*)d_in[1];
    const float* enc_b     = (const float*)d_in[2];
    const float* log_dt    = (const float*)d_in[3];
    const float* log_A_real= (const float*)d_in[4];
    const float* A_imag    = (const float*)d_in[5];
    const float* C_re      = (const float*)d_in[6];
    const float* C_im      = (const float*)d_in[7];
    const float* Dp        = (const float*)d_in[8];
    const float* out_w     = (const float*)d_in[9];
    const float* out_b     = (const float*)d_in[10];
    const float* dec_w     = (const float*)d_in[11];
    const float* dec_b     = (const float*)d_in[12];
    float* out = (float*)d_out;

    char* ws = (char*)d_ws;
    unsigned short* Wh = (unsigned short*)(ws);
    unsigned short* gy = (unsigned short*)(ws + 3211264);
    float* part        = (float*)(ws + 19988480);

    k_s4d<<<B_ * H_, 256, 0, stream>>>(x, enc_w, enc_b, log_dt, log_A_real,
                                       A_imag, C_re, C_im, Dp, out_w, Wh, gy);
    k_mix<<<B_ * 128, 256, 0, stream>>>(Wh, gy, out_b, dec_w, part);
    k_final<<<1, 512, 0, stream>>>(part, dec_b, out);
}